// Round 5
// baseline (669.959 us; speedup 1.0000x reference)
//
#include <hip/hip_runtime.h>
#include <stdint.h>

#define N_NODES 100000
#define N_EDGES 1600000
#define N_FEAT 512
#define N_HID 256
#define N_CLASS 40
#define H2S 48                      // padded H2 row stride (floats)

typedef float f32x4 __attribute__((ext_vector_type(4)));
typedef __bf16 bf16x8 __attribute__((ext_vector_type(8)));
typedef unsigned short u16x4 __attribute__((ext_vector_type(4)));
typedef unsigned short u16x8 __attribute__((ext_vector_type(8)));

__device__ __forceinline__ unsigned short f2bf(float f) {
  unsigned int u = __float_as_uint(f);
  unsigned int r = (u + 0x7FFFu + ((u >> 16) & 1u)) >> 16;
  return (unsigned short)r;
}
__device__ __forceinline__ float bf2f(unsigned short s) {
  return __uint_as_float(((unsigned int)s) << 16);
}

// ---------------- preamble: W1 transpose+cvt | W2 transpose+cvt | hist(+rank) ------
#define HIST_BLOCKS 1563            // ceil(1.6e6 / 1024), 4 edges/thread
#define W1T_BLOCKS  512
#define W2T_BLOCKS  48
__global__ __launch_bounds__(256) void k_pre(const float* __restrict__ W1,
                                             const float* __restrict__ W2,
                                             const int* __restrict__ ei,
                                             unsigned short* __restrict__ W1t,
                                             unsigned short* __restrict__ W2t,
                                             int* __restrict__ cnt,
                                             int* __restrict__ rank) {
  const int bid = blockIdx.x, tid = threadIdx.x;
  if (bid < HIST_BLOCKS) {
    #pragma unroll
    for (int k = 0; k < 4; ++k) {
      int e = bid * 1024 + k * 256 + tid;
      if (e < N_EDGES) rank[e] = atomicAdd(&cnt[ei[e]], 1);
    }
  } else if (bid < HIST_BLOCKS + W1T_BLOCKS) {
    int gid = (bid - HIST_BLOCKS) * 256 + tid;       // W1t[n][k]
    int n = gid >> 9, k = gid & 511;
    W1t[gid] = f2bf(W1[(long)k * N_HID + n]);
  } else {
    int gid = (bid - HIST_BLOCKS - W1T_BLOCKS) * 256 + tid;  // W2t[n][k], n pad 48
    int n = gid >> 8, k = gid & 255;
    W2t[gid] = (n < N_CLASS) ? f2bf(W2[(long)k * N_CLASS + n]) : (unsigned short)0;
  }
}

// ---------------- scan (3 passes) ----------------
__global__ __launch_bounds__(1024) void k_scan_a(const int* __restrict__ cnt,
                                                 int* __restrict__ rp,
                                                 int* __restrict__ bsum) {
  __shared__ int sm[1024];
  const int tid = threadIdx.x;
  const int i = blockIdx.x * 1024 + tid;
  int v = (i < N_NODES) ? cnt[i] : 0;
  sm[tid] = v;
  __syncthreads();
  #pragma unroll
  for (int d = 1; d < 1024; d <<= 1) {
    int t = (tid >= d) ? sm[tid - d] : 0;
    __syncthreads();
    sm[tid] += t;
    __syncthreads();
  }
  if (i < N_NODES) rp[i] = sm[tid] - v;
  if (tid == 1023) bsum[blockIdx.x] = sm[1023];
}

__global__ __launch_bounds__(128) void k_scan_b(const int* __restrict__ bsum,
                                                int* __restrict__ boffs,
                                                int* __restrict__ rp) {
  __shared__ int sm[128];
  const int tid = threadIdx.x;
  const int nb = (N_NODES + 1023) >> 10;
  int v = (tid < nb) ? bsum[tid] : 0;
  sm[tid] = v;
  __syncthreads();
  #pragma unroll
  for (int d = 1; d < 128; d <<= 1) {
    int t = (tid >= d) ? sm[tid - d] : 0;
    __syncthreads();
    sm[tid] += t;
    __syncthreads();
  }
  boffs[tid] = sm[tid] - v;
  if (tid == 127) rp[N_NODES] = sm[127];
}

__global__ void k_scan_c(int* __restrict__ rp, const int* __restrict__ boffs) {
  int i = blockIdx.x * 256 + threadIdx.x;
  if (i >= N_NODES) return;
  rp[i] += boffs[i >> 10];
}

// ---------------- fused: GEMM1 direct-from-global (even) + scatter (odd) ----------
// gemm role: 8 waves (2m x 4n), tile 128x256, wave tile 64x64, NO LDS, NO barriers.
// A frag loaded per-lane from X (fp32->bf16 in regs), B frag per-lane from L2-resident W1t.
#define NG1 782
__global__ __launch_bounds__(512) void k_fused1(const float* __restrict__ X,
                                                const unsigned short* __restrict__ W1t,
                                                const float* __restrict__ b1,
                                                unsigned short* __restrict__ H1,
                                                const int* __restrict__ ei,
                                                const float* __restrict__ ew,
                                                const int* __restrict__ rank,
                                                const int* __restrict__ rp,
                                                int2* __restrict__ cw) {
  const int t = threadIdx.x;

  if (blockIdx.x & 1) {                    // ---- scatter role ----
    int sb = blockIdx.x >> 1;
    #pragma unroll
    for (int k = 0; k < 4; ++k) {
      int e = sb * 2048 + k * 512 + t;
      if (e < N_EDGES) {
        int r = ei[e];
        int pos = rp[r] + rank[e];
        cw[pos] = make_int2(ei[N_EDGES + e], __float_as_int(ew[e]));
      }
    }
    return;
  }

  // ---- gemm role ----
  const int gb = blockIdx.x >> 1;
  const int lane = t & 63;
  const int wid = t >> 6;
  const int wm = wid >> 2, wn = wid & 3;   // 2 x 4 wave grid
  const long m0 = (long)gb * 128;
  const int lr = lane & 15;                // fragment row/col
  const int lk = (lane >> 4) * 8;          // k sub-offset

  const float* Ab[4];
  #pragma unroll
  for (int mt = 0; mt < 4; ++mt) {
    long r = m0 + wm * 64 + mt * 16 + lr;
    if (r >= N_NODES) r = N_NODES - 1;     // clamp: values unused, stay finite
    Ab[mt] = X + r * N_FEAT + lk;
  }
  const unsigned short* Bb[4];
  #pragma unroll
  for (int nt = 0; nt < 4; ++nt)
    Bb[nt] = W1t + (long)(wn * 64 + nt * 16 + lr) * N_FEAT + lk;

  f32x4 acc[4][4] = {};
  f32x4 xa[4], xb[4];
  bf16x8 bv[4];
  #pragma unroll
  for (int mt = 0; mt < 4; ++mt) { xa[mt] = *(const f32x4*)(Ab[mt]); xb[mt] = *(const f32x4*)(Ab[mt] + 4); }
  #pragma unroll
  for (int nt = 0; nt < 4; ++nt) bv[nt] = *(const bf16x8*)(Bb[nt]);

  #pragma unroll 2
  for (int k0 = 0; k0 < N_FEAT; k0 += 32) {
    // issue next step's loads (wrap-safe address, always valid)
    const int kn = (k0 + 32) & (N_FEAT - 1);
    f32x4 nxa[4], nxb[4];
    bf16x8 nbv[4];
    #pragma unroll
    for (int mt = 0; mt < 4; ++mt) {
      nxa[mt] = *(const f32x4*)(Ab[mt] + kn);
      nxb[mt] = *(const f32x4*)(Ab[mt] + kn + 4);
    }
    #pragma unroll
    for (int nt = 0; nt < 4; ++nt) nbv[nt] = *(const bf16x8*)(Bb[nt] + kn);

    // convert A to bf16 fragments
    bf16x8 av[4];
    #pragma unroll
    for (int mt = 0; mt < 4; ++mt) {
      bf16x8 v;
      v[0] = (__bf16)xa[mt][0]; v[1] = (__bf16)xa[mt][1];
      v[2] = (__bf16)xa[mt][2]; v[3] = (__bf16)xa[mt][3];
      v[4] = (__bf16)xb[mt][0]; v[5] = (__bf16)xb[mt][1];
      v[6] = (__bf16)xb[mt][2]; v[7] = (__bf16)xb[mt][3];
      av[mt] = v;
    }

    #pragma unroll
    for (int mt = 0; mt < 4; ++mt)
      #pragma unroll
      for (int nt = 0; nt < 4; ++nt)
        acc[mt][nt] = __builtin_amdgcn_mfma_f32_16x16x32_bf16(av[mt], bv[nt], acc[mt][nt], 0, 0, 0);

    #pragma unroll
    for (int mt = 0; mt < 4; ++mt) { xa[mt] = nxa[mt]; xb[mt] = nxb[mt]; }
    #pragma unroll
    for (int nt = 0; nt < 4; ++nt) bv[nt] = nbv[nt];
  }

  #pragma unroll
  for (int nt = 0; nt < 4; ++nt) {
    int col = wn * 64 + nt * 16 + lr;
    float bias = b1[col];
    #pragma unroll
    for (int mt = 0; mt < 4; ++mt) {
      #pragma unroll
      for (int i = 0; i < 4; ++i) {
        long row = m0 + wm * 64 + mt * 16 + (lane >> 4) * 4 + i;
        if (row < N_NODES) H1[row * N_HID + col] = f2bf(acc[mt][nt][i] + bias);
      }
    }
  }
}

// ---------------- SPMM1 + relu: H1r = bf16(relu(A @ H1)), 8-deep gather pipeline ----
__global__ __launch_bounds__(256) void k_spmm1(const int* __restrict__ row_ptr,
                                               const int2* __restrict__ cw,
                                               const unsigned short* __restrict__ H1,
                                               unsigned short* __restrict__ H1r) {
  int r = blockIdx.x * 4 + (threadIdx.x >> 6);
  int lane = threadIdx.x & 63;
  if (r >= N_NODES) return;
  int s = row_ptr[r], e = row_ptr[r + 1];
  float a0 = 0.f, a1 = 0.f, a2 = 0.f, a3 = 0.f;
  const unsigned short* Hb = H1 + lane * 4;
  int i = s;
  for (; i + 8 <= e; i += 8) {
    int2 c0 = cw[i + 0]; int2 c1 = cw[i + 1]; int2 c2 = cw[i + 2]; int2 c3 = cw[i + 3];
    int2 c4 = cw[i + 4]; int2 c5 = cw[i + 5]; int2 c6 = cw[i + 6]; int2 c7 = cw[i + 7];
    u16x4 h0 = *(const u16x4*)(Hb + (long)c0.x * N_HID);
    u16x4 h1 = *(const u16x4*)(Hb + (long)c1.x * N_HID);
    u16x4 h2 = *(const u16x4*)(Hb + (long)c2.x * N_HID);
    u16x4 h3 = *(const u16x4*)(Hb + (long)c3.x * N_HID);
    u16x4 h4 = *(const u16x4*)(Hb + (long)c4.x * N_HID);
    u16x4 h5 = *(const u16x4*)(Hb + (long)c5.x * N_HID);
    u16x4 h6 = *(const u16x4*)(Hb + (long)c6.x * N_HID);
    u16x4 h7 = *(const u16x4*)(Hb + (long)c7.x * N_HID);
    float w0 = __int_as_float(c0.y), w1 = __int_as_float(c1.y);
    float w2 = __int_as_float(c2.y), w3 = __int_as_float(c3.y);
    float w4 = __int_as_float(c4.y), w5 = __int_as_float(c5.y);
    float w6 = __int_as_float(c6.y), w7 = __int_as_float(c7.y);
    a0 += w0 * bf2f(h0[0]); a1 += w0 * bf2f(h0[1]); a2 += w0 * bf2f(h0[2]); a3 += w0 * bf2f(h0[3]);
    a0 += w1 * bf2f(h1[0]); a1 += w1 * bf2f(h1[1]); a2 += w1 * bf2f(h1[2]); a3 += w1 * bf2f(h1[3]);
    a0 += w2 * bf2f(h2[0]); a1 += w2 * bf2f(h2[1]); a2 += w2 * bf2f(h2[2]); a3 += w2 * bf2f(h2[3]);
    a0 += w3 * bf2f(h3[0]); a1 += w3 * bf2f(h3[1]); a2 += w3 * bf2f(h3[2]); a3 += w3 * bf2f(h3[3]);
    a0 += w4 * bf2f(h4[0]); a1 += w4 * bf2f(h4[1]); a2 += w4 * bf2f(h4[2]); a3 += w4 * bf2f(h4[3]);
    a0 += w5 * bf2f(h5[0]); a1 += w5 * bf2f(h5[1]); a2 += w5 * bf2f(h5[2]); a3 += w5 * bf2f(h5[3]);
    a0 += w6 * bf2f(h6[0]); a1 += w6 * bf2f(h6[1]); a2 += w6 * bf2f(h6[2]); a3 += w6 * bf2f(h6[3]);
    a0 += w7 * bf2f(h7[0]); a1 += w7 * bf2f(h7[1]); a2 += w7 * bf2f(h7[2]); a3 += w7 * bf2f(h7[3]);
  }
  for (; i < e; ++i) {
    int2 cwv = cw[i];
    float w = __int_as_float(cwv.y);
    u16x4 hv = *(const u16x4*)(Hb + (long)cwv.x * N_HID);
    a0 += w * bf2f(hv[0]);
    a1 += w * bf2f(hv[1]);
    a2 += w * bf2f(hv[2]);
    a3 += w * bf2f(hv[3]);
  }
  u16x4 o;
  o[0] = f2bf(fmaxf(a0, 0.f));
  o[1] = f2bf(fmaxf(a1, 0.f));
  o[2] = f2bf(fmaxf(a2, 0.f));
  o[3] = f2bf(fmaxf(a3, 0.f));
  *(u16x4*)(H1r + (long)r * N_HID + lane * 4) = o;
}

// ---------------- GEMM2 direct-from-global: H2[.][48] = H1r @ W2 + b2 -------------
// 4 waves, each 32 rows x 48 cols; W2t (24 KB) L1/L2-resident; NO LDS, NO barriers.
__global__ __launch_bounds__(256) void k_gemm2(const unsigned short* __restrict__ H1r,
                                               const unsigned short* __restrict__ W2t,
                                               const float* __restrict__ b2,
                                               float* __restrict__ H2) {
  const int t = threadIdx.x;
  const int lane = t & 63;
  const int wid = t >> 6;
  const long m0 = (long)blockIdx.x * 128;
  const int lr = lane & 15;
  const int lk = (lane >> 4) * 8;

  const unsigned short* Ab[2];
  #pragma unroll
  for (int mt = 0; mt < 2; ++mt) {
    long r = m0 + wid * 32 + mt * 16 + lr;
    if (r >= N_NODES) r = N_NODES - 1;
    Ab[mt] = H1r + r * N_HID + lk;
  }
  const unsigned short* Bb[3];
  #pragma unroll
  for (int nt = 0; nt < 3; ++nt)
    Bb[nt] = W2t + (long)(nt * 16 + lr) * N_HID + lk;

  f32x4 acc[2][3] = {};
  #pragma unroll
  for (int k0 = 0; k0 < N_HID; k0 += 32) {
    bf16x8 av[2], bvv[3];
    #pragma unroll
    for (int mt = 0; mt < 2; ++mt) av[mt] = *(const bf16x8*)(Ab[mt] + k0);
    #pragma unroll
    for (int nt = 0; nt < 3; ++nt) bvv[nt] = *(const bf16x8*)(Bb[nt] + k0);
    #pragma unroll
    for (int mt = 0; mt < 2; ++mt)
      #pragma unroll
      for (int nt = 0; nt < 3; ++nt)
        acc[mt][nt] = __builtin_amdgcn_mfma_f32_16x16x32_bf16(av[mt], bvv[nt], acc[mt][nt], 0, 0, 0);
  }

  #pragma unroll
  for (int nt = 0; nt < 3; ++nt) {
    int col = nt * 16 + lr;
    if (col < N_CLASS) {
      float bias = b2[col];
      #pragma unroll
      for (int mt = 0; mt < 2; ++mt) {
        #pragma unroll
        for (int i = 0; i < 4; ++i) {
          long row = m0 + wid * 32 + mt * 16 + (lane >> 4) * 4 + i;
          if (row < N_NODES) H2[row * H2S + col] = acc[mt][nt][i] + bias;
        }
      }
    }
  }
}

// ---------------- SPMM2 + log_softmax fused, 8-deep gather pipeline ----------------
__global__ __launch_bounds__(256) void k_spmm2_lsm(const int* __restrict__ row_ptr,
                                                   const int2* __restrict__ cw,
                                                   const float* __restrict__ H2,
                                                   float* __restrict__ out) {
  int r = blockIdx.x * 4 + (threadIdx.x >> 6);
  int lane = threadIdx.x & 63;
  if (r >= N_NODES) return;
  int s = row_ptr[r], e = row_ptr[r + 1];
  float acc = 0.f;
  const bool act = lane < N_CLASS;
  int i = s;
  for (; i + 8 <= e; i += 8) {
    int2 c0 = cw[i + 0]; int2 c1 = cw[i + 1]; int2 c2 = cw[i + 2]; int2 c3 = cw[i + 3];
    int2 c4 = cw[i + 4]; int2 c5 = cw[i + 5]; int2 c6 = cw[i + 6]; int2 c7 = cw[i + 7];
    float h0 = 0.f, h1 = 0.f, h2 = 0.f, h3 = 0.f, h4 = 0.f, h5 = 0.f, h6 = 0.f, h7 = 0.f;
    if (act) {
      h0 = H2[(long)c0.x * H2S + lane];
      h1 = H2[(long)c1.x * H2S + lane];
      h2 = H2[(long)c2.x * H2S + lane];
      h3 = H2[(long)c3.x * H2S + lane];
      h4 = H2[(long)c4.x * H2S + lane];
      h5 = H2[(long)c5.x * H2S + lane];
      h6 = H2[(long)c6.x * H2S + lane];
      h7 = H2[(long)c7.x * H2S + lane];
    }
    acc += __int_as_float(c0.y) * h0;
    acc += __int_as_float(c1.y) * h1;
    acc += __int_as_float(c2.y) * h2;
    acc += __int_as_float(c3.y) * h3;
    acc += __int_as_float(c4.y) * h4;
    acc += __int_as_float(c5.y) * h5;
    acc += __int_as_float(c6.y) * h6;
    acc += __int_as_float(c7.y) * h7;
  }
  for (; i < e; ++i) {
    int2 cwv = cw[i];
    if (act) acc += __int_as_float(cwv.y) * H2[(long)cwv.x * H2S + lane];
  }
  float v = act ? acc : -INFINITY;
  float m = v;
  #pragma unroll
  for (int d = 32; d > 0; d >>= 1) m = fmaxf(m, __shfl_xor(m, d));
  float ex = act ? __expf(v - m) : 0.f;
  float ssum = ex;
  #pragma unroll
  for (int d = 32; d > 0; d >>= 1) ssum += __shfl_xor(ssum, d);
  float ls = __logf(ssum);
  if (act) out[(long)r * N_CLASS + lane] = v - m - ls;
}

extern "C" void kernel_launch(void* const* d_in, const int* in_sizes, int n_in,
                              void* d_out, int out_size, void* d_ws, size_t ws_size,
                              hipStream_t stream) {
  (void)in_sizes; (void)n_in; (void)out_size; (void)ws_size;
  const float* X  = (const float*)d_in[0];
  const int*   EI = (const int*)d_in[1];
  const float* EW = (const float*)d_in[2];
  const float* W1 = (const float*)d_in[3];
  const float* b1 = (const float*)d_in[4];
  const float* W2 = (const float*)d_in[5];
  const float* b2 = (const float*)d_in[6];
  float* out = (float*)d_out;

  char* p = (char*)d_ws;
  auto take = [&](size_t bytes) {
    char* r = p;
    p += (bytes + 511) & ~(size_t)511;
    return r;
  };
  unsigned short* W1t   = (unsigned short*)take((size_t)N_HID * N_FEAT * 2);
  unsigned short* W2t   = (unsigned short*)take((size_t)48 * N_HID * 2);
  int*            cnt   = (int*)take((size_t)N_NODES * 4);
  int*            rp    = (int*)take((size_t)(N_NODES + 1) * 4);
  int*            bsum  = (int*)take((size_t)128 * 4);
  int*            boffs = (int*)take((size_t)128 * 4);
  int*            rank  = (int*)take((size_t)N_EDGES * 4);
  int2*           cw    = (int2*)take((size_t)N_EDGES * 8);
  unsigned short* H1    = (unsigned short*)take((size_t)N_NODES * N_HID * 2);
  unsigned short* H1r   = (unsigned short*)take((size_t)N_NODES * N_HID * 2);
  float*          H2    = (float*)take((size_t)N_NODES * H2S * 4);

  const int NB_SCAN = (N_NODES + 1023) / 1024;

  hipMemsetAsync(cnt, 0, (size_t)N_NODES * 4, stream);
  k_pre<<<HIST_BLOCKS + W1T_BLOCKS + W2T_BLOCKS, 256, 0, stream>>>(W1, W2, EI, W1t, W2t, cnt, rank);
  k_scan_a<<<NB_SCAN, 1024, 0, stream>>>(cnt, rp, bsum);
  k_scan_b<<<1, 128, 0, stream>>>(bsum, boffs, rp);
  k_scan_c<<<(N_NODES + 255) / 256, 256, 0, stream>>>(rp, boffs);
  k_fused1<<<2 * NG1, 512, 0, stream>>>(X, W1t, b1, H1, EI, EW, rank, rp, cw);
  k_spmm1<<<(N_NODES + 3) / 4, 256, 0, stream>>>(rp, cw, H1, H1r);
  k_gemm2<<<(N_NODES + 127) / 128, 256, 0, stream>>>(H1r, W2t, b2, H2);
  k_spmm2_lsm<<<(N_NODES + 3) / 4, 256, 0, stream>>>(rp, cw, H2, out);
}

// Round 6
// 565.786 us; speedup vs baseline: 1.1841x; 1.1841x over previous
//
#include <hip/hip_runtime.h>
#include <stdint.h>

#define N_NODES 100000
#define N_EDGES 1600000
#define N_FEAT 512
#define N_HID 256
#define N_CLASS 40
#define H2S 48                      // padded H2 row stride (floats)

typedef float f32x4 __attribute__((ext_vector_type(4)));
typedef __bf16 bf16x8 __attribute__((ext_vector_type(8)));
typedef unsigned short u16x4 __attribute__((ext_vector_type(4)));
typedef unsigned short u16x8 __attribute__((ext_vector_type(8)));

__device__ __forceinline__ unsigned short f2bf(float f) {
  unsigned int u = __float_as_uint(f);
  unsigned int r = (u + 0x7FFFu + ((u >> 16) & 1u)) >> 16;
  return (unsigned short)r;
}
__device__ __forceinline__ float bf2f(unsigned short s) {
  return __uint_as_float(((unsigned int)s) << 16);
}

// ---------------- preamble: W1 transpose+cvt | W2 transpose+cvt | hist(+rank) ------
#define HIST_BLOCKS 1563
#define W1T_BLOCKS  512
#define W2T_BLOCKS  48
__global__ __launch_bounds__(256) void k_pre(const float* __restrict__ W1,
                                             const float* __restrict__ W2,
                                             const int* __restrict__ ei,
                                             unsigned short* __restrict__ W1t,
                                             unsigned short* __restrict__ W2t,
                                             int* __restrict__ cnt,
                                             int* __restrict__ rank) {
  const int bid = blockIdx.x, tid = threadIdx.x;
  if (bid < HIST_BLOCKS) {
    #pragma unroll
    for (int k = 0; k < 4; ++k) {
      int e = bid * 1024 + k * 256 + tid;
      if (e < N_EDGES) rank[e] = atomicAdd(&cnt[ei[e]], 1);
    }
  } else if (bid < HIST_BLOCKS + W1T_BLOCKS) {
    int gid = (bid - HIST_BLOCKS) * 256 + tid;       // W1t[n][k]
    int n = gid >> 9, k = gid & 511;
    W1t[gid] = f2bf(W1[(long)k * N_HID + n]);
  } else {
    int gid = (bid - HIST_BLOCKS - W1T_BLOCKS) * 256 + tid;  // W2t[n][k], n pad 48
    int n = gid >> 8, k = gid & 255;
    W2t[gid] = (n < N_CLASS) ? f2bf(W2[(long)k * N_CLASS + n]) : (unsigned short)0;
  }
}

// ---------------- scan (3 passes) ----------------
__global__ __launch_bounds__(1024) void k_scan_a(const int* __restrict__ cnt,
                                                 int* __restrict__ rp,
                                                 int* __restrict__ bsum) {
  __shared__ int sm[1024];
  const int tid = threadIdx.x;
  const int i = blockIdx.x * 1024 + tid;
  int v = (i < N_NODES) ? cnt[i] : 0;
  sm[tid] = v;
  __syncthreads();
  #pragma unroll
  for (int d = 1; d < 1024; d <<= 1) {
    int t = (tid >= d) ? sm[tid - d] : 0;
    __syncthreads();
    sm[tid] += t;
    __syncthreads();
  }
  if (i < N_NODES) rp[i] = sm[tid] - v;
  if (tid == 1023) bsum[blockIdx.x] = sm[1023];
}

__global__ __launch_bounds__(128) void k_scan_b(const int* __restrict__ bsum,
                                                int* __restrict__ boffs,
                                                int* __restrict__ rp) {
  __shared__ int sm[128];
  const int tid = threadIdx.x;
  const int nb = (N_NODES + 1023) >> 10;
  int v = (tid < nb) ? bsum[tid] : 0;
  sm[tid] = v;
  __syncthreads();
  #pragma unroll
  for (int d = 1; d < 128; d <<= 1) {
    int t = (tid >= d) ? sm[tid - d] : 0;
    __syncthreads();
    sm[tid] += t;
    __syncthreads();
  }
  boffs[tid] = sm[tid] - v;
  if (tid == 127) rp[N_NODES] = sm[127];
}

__global__ void k_scan_c(int* __restrict__ rp, const int* __restrict__ boffs) {
  int i = blockIdx.x * 256 + threadIdx.x;
  if (i >= N_NODES) return;
  rp[i] += boffs[i >> 10];
}

// ---------------- fused: GEMM1 hybrid (A direct-global, B in LDS) + scatter -------
// grid = 3*NG1: bid%3==2 -> scatter (2048 edges), else gemm.
// gemm: 1564 blocks = 782 m-blocks x 2 n-panels. 8 waves (2m x 4n), wave tile 64x32.
// B panel chunk: 128 cols x 128 k staged in LDS [128][132] (pad 4 -> conflict-free),
// restaged 4x per block with next-chunk loads issued early (T14).
#define NG1 782
__global__ __launch_bounds__(512) void k_fused1(const float* __restrict__ X,
                                                const unsigned short* __restrict__ W1t,
                                                const float* __restrict__ b1,
                                                unsigned short* __restrict__ H1,
                                                const int* __restrict__ ei,
                                                const float* __restrict__ ew,
                                                const int* __restrict__ rank,
                                                const int* __restrict__ rp,
                                                int2* __restrict__ cw) {
  const int bid = blockIdx.x;
  const int t = threadIdx.x;
  const int r3 = bid % 3;

  if (r3 == 2) {                           // ---- scatter role ----
    int sb = bid / 3;
    #pragma unroll
    for (int k = 0; k < 4; ++k) {
      int e = sb * 2048 + k * 512 + t;
      if (e < N_EDGES) {
        int r = ei[e];
        int pos = rp[r] + rank[e];
        cw[pos] = make_int2(ei[N_EDGES + e], __float_as_int(ew[e]));
      }
    }
    return;
  }

  // ---- gemm role ----
  __shared__ unsigned short Bs[128][132];
  const int gb = (bid / 3) * 2 + r3;       // 0..1563
  const int mblk = gb >> 1, panel = gb & 1;
  const long m0 = (long)mblk * 128;
  const int n0 = panel * 128;
  const int lane = t & 63;
  const int wid = t >> 6;
  const int wm = wid >> 2, wn = wid & 3;   // 2 x 4 wave grid, wave tile 64x32
  const int lr = lane & 15;
  const int lkg = lane >> 4;               // k-group 0..3

  // A row base pointers (direct from X, fp32), clamped
  const float* Ap[4];
  #pragma unroll
  for (int mt = 0; mt < 4; ++mt) {
    long r = m0 + wm * 64 + mt * 16 + lr;
    if (r >= N_NODES) r = N_NODES - 1;     // values unused (store-guarded)
    Ap[mt] = X + r * N_FEAT + lkg * 8;
  }

  // B stage: thread t handles row = t>>2, seg = t&3 (32 shorts)
  const int brow = t >> 2, bseg = t & 3;
  const unsigned short* Bsrc = W1t + (long)(n0 + brow) * N_FEAT + bseg * 32;

  f32x4 acc[4][2] = {};
  u16x8 st0, st1, st2, st3;
  st0 = *(const u16x8*)(Bsrc + 0);
  st1 = *(const u16x8*)(Bsrc + 8);
  st2 = *(const u16x8*)(Bsrc + 16);
  st3 = *(const u16x8*)(Bsrc + 24);

  #pragma unroll 1
  for (int c = 0; c < 4; ++c) {
    __syncthreads();                       // prev chunk's reads done
    *(u16x8*)&Bs[brow][bseg * 32 + 0]  = st0;
    *(u16x8*)&Bs[brow][bseg * 32 + 8]  = st1;
    *(u16x8*)&Bs[brow][bseg * 32 + 16] = st2;
    *(u16x8*)&Bs[brow][bseg * 32 + 24] = st3;
    __syncthreads();
    if (c < 3) {                           // early-issue next chunk (completes under MFMA)
      const unsigned short* nsrc = Bsrc + (c + 1) * 128;
      st0 = *(const u16x8*)(nsrc + 0);
      st1 = *(const u16x8*)(nsrc + 8);
      st2 = *(const u16x8*)(nsrc + 16);
      st3 = *(const u16x8*)(nsrc + 24);
    }

    #pragma unroll
    for (int s = 0; s < 4; ++s) {
      const int ko = c * 128 + s * 32;
      f32x4 xa[4], xb[4];
      #pragma unroll
      for (int mt = 0; mt < 4; ++mt) {
        xa[mt] = *(const f32x4*)(Ap[mt] + ko);
        xb[mt] = *(const f32x4*)(Ap[mt] + ko + 4);
      }
      bf16x8 bv[2];
      #pragma unroll
      for (int nt = 0; nt < 2; ++nt)
        bv[nt] = *(const bf16x8*)&Bs[wn * 32 + nt * 16 + lr][s * 32 + lkg * 8];
      bf16x8 av[4];
      #pragma unroll
      for (int mt = 0; mt < 4; ++mt) {
        bf16x8 v;
        v[0] = (__bf16)xa[mt][0]; v[1] = (__bf16)xa[mt][1];
        v[2] = (__bf16)xa[mt][2]; v[3] = (__bf16)xa[mt][3];
        v[4] = (__bf16)xb[mt][0]; v[5] = (__bf16)xb[mt][1];
        v[6] = (__bf16)xb[mt][2]; v[7] = (__bf16)xb[mt][3];
        av[mt] = v;
      }
      #pragma unroll
      for (int mt = 0; mt < 4; ++mt)
        #pragma unroll
        for (int nt = 0; nt < 2; ++nt)
          acc[mt][nt] = __builtin_amdgcn_mfma_f32_16x16x32_bf16(av[mt], bv[nt], acc[mt][nt], 0, 0, 0);
    }
  }

  #pragma unroll
  for (int nt = 0; nt < 2; ++nt) {
    int col = n0 + wn * 32 + nt * 16 + lr;
    float bias = b1[col];
    #pragma unroll
    for (int mt = 0; mt < 4; ++mt) {
      #pragma unroll
      for (int i = 0; i < 4; ++i) {
        long row = m0 + wm * 64 + mt * 16 + lkg * 4 + i;
        if (row < N_NODES) H1[row * N_HID + col] = f2bf(acc[mt][nt][i] + bias);
      }
    }
  }
}

// ---------------- SPMM1 + relu: H1r = bf16(relu(A @ H1)), 8-deep gather pipeline ----
__global__ __launch_bounds__(256) void k_spmm1(const int* __restrict__ row_ptr,
                                               const int2* __restrict__ cw,
                                               const unsigned short* __restrict__ H1,
                                               unsigned short* __restrict__ H1r) {
  int r = blockIdx.x * 4 + (threadIdx.x >> 6);
  int lane = threadIdx.x & 63;
  if (r >= N_NODES) return;
  int s = row_ptr[r], e = row_ptr[r + 1];
  float a0 = 0.f, a1 = 0.f, a2 = 0.f, a3 = 0.f;
  const unsigned short* Hb = H1 + lane * 4;
  int i = s;
  for (; i + 8 <= e; i += 8) {
    int2 c0 = cw[i + 0]; int2 c1 = cw[i + 1]; int2 c2 = cw[i + 2]; int2 c3 = cw[i + 3];
    int2 c4 = cw[i + 4]; int2 c5 = cw[i + 5]; int2 c6 = cw[i + 6]; int2 c7 = cw[i + 7];
    u16x4 h0 = *(const u16x4*)(Hb + (long)c0.x * N_HID);
    u16x4 h1 = *(const u16x4*)(Hb + (long)c1.x * N_HID);
    u16x4 h2 = *(const u16x4*)(Hb + (long)c2.x * N_HID);
    u16x4 h3 = *(const u16x4*)(Hb + (long)c3.x * N_HID);
    u16x4 h4 = *(const u16x4*)(Hb + (long)c4.x * N_HID);
    u16x4 h5 = *(const u16x4*)(Hb + (long)c5.x * N_HID);
    u16x4 h6 = *(const u16x4*)(Hb + (long)c6.x * N_HID);
    u16x4 h7 = *(const u16x4*)(Hb + (long)c7.x * N_HID);
    float w0 = __int_as_float(c0.y), w1 = __int_as_float(c1.y);
    float w2 = __int_as_float(c2.y), w3 = __int_as_float(c3.y);
    float w4 = __int_as_float(c4.y), w5 = __int_as_float(c5.y);
    float w6 = __int_as_float(c6.y), w7 = __int_as_float(c7.y);
    a0 += w0 * bf2f(h0[0]); a1 += w0 * bf2f(h0[1]); a2 += w0 * bf2f(h0[2]); a3 += w0 * bf2f(h0[3]);
    a0 += w1 * bf2f(h1[0]); a1 += w1 * bf2f(h1[1]); a2 += w1 * bf2f(h1[2]); a3 += w1 * bf2f(h1[3]);
    a0 += w2 * bf2f(h2[0]); a1 += w2 * bf2f(h2[1]); a2 += w2 * bf2f(h2[2]); a3 += w2 * bf2f(h2[3]);
    a0 += w3 * bf2f(h3[0]); a1 += w3 * bf2f(h3[1]); a2 += w3 * bf2f(h3[2]); a3 += w3 * bf2f(h3[3]);
    a0 += w4 * bf2f(h4[0]); a1 += w4 * bf2f(h4[1]); a2 += w4 * bf2f(h4[2]); a3 += w4 * bf2f(h4[3]);
    a0 += w5 * bf2f(h5[0]); a1 += w5 * bf2f(h5[1]); a2 += w5 * bf2f(h5[2]); a3 += w5 * bf2f(h5[3]);
    a0 += w6 * bf2f(h6[0]); a1 += w6 * bf2f(h6[1]); a2 += w6 * bf2f(h6[2]); a3 += w6 * bf2f(h6[3]);
    a0 += w7 * bf2f(h7[0]); a1 += w7 * bf2f(h7[1]); a2 += w7 * bf2f(h7[2]); a3 += w7 * bf2f(h7[3]);
  }
  for (; i < e; ++i) {
    int2 cwv = cw[i];
    float w = __int_as_float(cwv.y);
    u16x4 hv = *(const u16x4*)(Hb + (long)cwv.x * N_HID);
    a0 += w * bf2f(hv[0]);
    a1 += w * bf2f(hv[1]);
    a2 += w * bf2f(hv[2]);
    a3 += w * bf2f(hv[3]);
  }
  u16x4 o;
  o[0] = f2bf(fmaxf(a0, 0.f));
  o[1] = f2bf(fmaxf(a1, 0.f));
  o[2] = f2bf(fmaxf(a2, 0.f));
  o[3] = f2bf(fmaxf(a3, 0.f));
  *(u16x4*)(H1r + (long)r * N_HID + lane * 4) = o;
}

// ---------------- GEMM2 direct-from-global: H2[.][48] = H1r @ W2 + b2 -------------
__global__ __launch_bounds__(256) void k_gemm2(const unsigned short* __restrict__ H1r,
                                               const unsigned short* __restrict__ W2t,
                                               const float* __restrict__ b2,
                                               float* __restrict__ H2) {
  const int t = threadIdx.x;
  const int lane = t & 63;
  const int wid = t >> 6;
  const long m0 = (long)blockIdx.x * 128;
  const int lr = lane & 15;
  const int lk = (lane >> 4) * 8;

  const unsigned short* Ab[2];
  #pragma unroll
  for (int mt = 0; mt < 2; ++mt) {
    long r = m0 + wid * 32 + mt * 16 + lr;
    if (r >= N_NODES) r = N_NODES - 1;
    Ab[mt] = H1r + r * N_HID + lk;
  }
  const unsigned short* Bb[3];
  #pragma unroll
  for (int nt = 0; nt < 3; ++nt)
    Bb[nt] = W2t + (long)(nt * 16 + lr) * N_HID + lk;

  f32x4 acc[2][3] = {};
  #pragma unroll
  for (int k0 = 0; k0 < N_HID; k0 += 32) {
    bf16x8 av[2], bvv[3];
    #pragma unroll
    for (int mt = 0; mt < 2; ++mt) av[mt] = *(const bf16x8*)(Ab[mt] + k0);
    #pragma unroll
    for (int nt = 0; nt < 3; ++nt) bvv[nt] = *(const bf16x8*)(Bb[nt] + k0);
    #pragma unroll
    for (int mt = 0; mt < 2; ++mt)
      #pragma unroll
      for (int nt = 0; nt < 3; ++nt)
        acc[mt][nt] = __builtin_amdgcn_mfma_f32_16x16x32_bf16(av[mt], bvv[nt], acc[mt][nt], 0, 0, 0);
  }

  #pragma unroll
  for (int nt = 0; nt < 3; ++nt) {
    int col = nt * 16 + lr;
    if (col < N_CLASS) {
      float bias = b2[col];
      #pragma unroll
      for (int mt = 0; mt < 2; ++mt) {
        #pragma unroll
        for (int i = 0; i < 4; ++i) {
          long row = m0 + wid * 32 + mt * 16 + (lane >> 4) * 4 + i;
          if (row < N_NODES) H2[row * H2S + col] = acc[mt][nt][i] + bias;
        }
      }
    }
  }
}

// ---------------- SPMM2 + log_softmax fused, 8-deep gather pipeline ----------------
__global__ __launch_bounds__(256) void k_spmm2_lsm(const int* __restrict__ row_ptr,
                                                   const int2* __restrict__ cw,
                                                   const float* __restrict__ H2,
                                                   float* __restrict__ out) {
  int r = blockIdx.x * 4 + (threadIdx.x >> 6);
  int lane = threadIdx.x & 63;
  if (r >= N_NODES) return;
  int s = row_ptr[r], e = row_ptr[r + 1];
  float acc = 0.f;
  const bool act = lane < N_CLASS;
  int i = s;
  for (; i + 8 <= e; i += 8) {
    int2 c0 = cw[i + 0]; int2 c1 = cw[i + 1]; int2 c2 = cw[i + 2]; int2 c3 = cw[i + 3];
    int2 c4 = cw[i + 4]; int2 c5 = cw[i + 5]; int2 c6 = cw[i + 6]; int2 c7 = cw[i + 7];
    float h0 = 0.f, h1 = 0.f, h2 = 0.f, h3 = 0.f, h4 = 0.f, h5 = 0.f, h6 = 0.f, h7 = 0.f;
    if (act) {
      h0 = H2[(long)c0.x * H2S + lane];
      h1 = H2[(long)c1.x * H2S + lane];
      h2 = H2[(long)c2.x * H2S + lane];
      h3 = H2[(long)c3.x * H2S + lane];
      h4 = H2[(long)c4.x * H2S + lane];
      h5 = H2[(long)c5.x * H2S + lane];
      h6 = H2[(long)c6.x * H2S + lane];
      h7 = H2[(long)c7.x * H2S + lane];
    }
    acc += __int_as_float(c0.y) * h0;
    acc += __int_as_float(c1.y) * h1;
    acc += __int_as_float(c2.y) * h2;
    acc += __int_as_float(c3.y) * h3;
    acc += __int_as_float(c4.y) * h4;
    acc += __int_as_float(c5.y) * h5;
    acc += __int_as_float(c6.y) * h6;
    acc += __int_as_float(c7.y) * h7;
  }
  for (; i < e; ++i) {
    int2 cwv = cw[i];
    if (act) acc += __int_as_float(cwv.y) * H2[(long)cwv.x * H2S + lane];
  }
  float v = act ? acc : -INFINITY;
  float m = v;
  #pragma unroll
  for (int d = 32; d > 0; d >>= 1) m = fmaxf(m, __shfl_xor(m, d));
  float ex = act ? __expf(v - m) : 0.f;
  float ssum = ex;
  #pragma unroll
  for (int d = 32; d > 0; d >>= 1) ssum += __shfl_xor(ssum, d);
  float ls = __logf(ssum);
  if (act) out[(long)r * N_CLASS + lane] = v - m - ls;
}

extern "C" void kernel_launch(void* const* d_in, const int* in_sizes, int n_in,
                              void* d_out, int out_size, void* d_ws, size_t ws_size,
                              hipStream_t stream) {
  (void)in_sizes; (void)n_in; (void)out_size; (void)ws_size;
  const float* X  = (const float*)d_in[0];
  const int*   EI = (const int*)d_in[1];
  const float* EW = (const float*)d_in[2];
  const float* W1 = (const float*)d_in[3];
  const float* b1 = (const float*)d_in[4];
  const float* W2 = (const float*)d_in[5];
  const float* b2 = (const float*)d_in[6];
  float* out = (float*)d_out;

  char* p = (char*)d_ws;
  auto take = [&](size_t bytes) {
    char* r = p;
    p += (bytes + 511) & ~(size_t)511;
    return r;
  };
  unsigned short* W1t   = (unsigned short*)take((size_t)N_HID * N_FEAT * 2);
  unsigned short* W2t   = (unsigned short*)take((size_t)48 * N_HID * 2);
  int*            cnt   = (int*)take((size_t)N_NODES * 4);
  int*            rp    = (int*)take((size_t)(N_NODES + 1) * 4);
  int*            bsum  = (int*)take((size_t)128 * 4);
  int*            boffs = (int*)take((size_t)128 * 4);
  int*            rank  = (int*)take((size_t)N_EDGES * 4);
  int2*           cw    = (int2*)take((size_t)N_EDGES * 8);
  unsigned short* H1    = (unsigned short*)take((size_t)N_NODES * N_HID * 2);
  unsigned short* H1r   = (unsigned short*)take((size_t)N_NODES * N_HID * 2);
  float*          H2    = (float*)take((size_t)N_NODES * H2S * 4);

  const int NB_SCAN = (N_NODES + 1023) / 1024;

  hipMemsetAsync(cnt, 0, (size_t)N_NODES * 4, stream);
  k_pre<<<HIST_BLOCKS + W1T_BLOCKS + W2T_BLOCKS, 256, 0, stream>>>(W1, W2, EI, W1t, W2t, cnt, rank);
  k_scan_a<<<NB_SCAN, 1024, 0, stream>>>(cnt, rp, bsum);
  k_scan_b<<<1, 128, 0, stream>>>(bsum, boffs, rp);
  k_scan_c<<<(N_NODES + 255) / 256, 256, 0, stream>>>(rp, boffs);
  k_fused1<<<3 * NG1, 512, 0, stream>>>(X, W1t, b1, H1, EI, EW, rank, rp, cw);
  k_spmm1<<<(N_NODES + 3) / 4, 256, 0, stream>>>(rp, cw, H1, H1r);
  k_gemm2<<<(N_NODES + 127) / 128, 256, 0, stream>>>(H1r, W2t, b2, H2);
  k_spmm2_lsm<<<(N_NODES + 3) / 4, 256, 0, stream>>>(rp, cw, H2, out);
}

// Round 7
// 461.425 us; speedup vs baseline: 1.4519x; 1.2262x over previous
//
#include <hip/hip_runtime.h>
#include <stdint.h>

#define N_NODES 100000
#define N_EDGES 1600000
#define N_FEAT 512
#define N_HID 256
#define N_CLASS 40
#define H2S 48                      // padded H2 row stride (floats)

typedef float f32x4 __attribute__((ext_vector_type(4)));
typedef __bf16 bf16x8 __attribute__((ext_vector_type(8)));
typedef unsigned short u16x4 __attribute__((ext_vector_type(4)));
typedef unsigned short u16x8 __attribute__((ext_vector_type(8)));

__device__ __forceinline__ unsigned short f2bf(float f) {
  unsigned int u = __float_as_uint(f);
  unsigned int r = (u + 0x7FFFu + ((u >> 16) & 1u)) >> 16;
  return (unsigned short)r;
}
__device__ __forceinline__ float bf2f(unsigned short s) {
  return __uint_as_float(((unsigned int)s) << 16);
}

__device__ __forceinline__ void gll16(const void* g, void* l) {
  __builtin_amdgcn_global_load_lds(
      (const __attribute__((address_space(1))) unsigned int*)g,
      (__attribute__((address_space(3))) unsigned int*)l, 16, 0, 0);
}

// ---------------- preamble: W1 transpose+cvt | W2 transpose+cvt | hist(+rank) ------
#define HIST_BLOCKS 1563
#define W1T_BLOCKS  512
#define W2T_BLOCKS  48
__global__ __launch_bounds__(256) void k_pre(const float* __restrict__ W1,
                                             const float* __restrict__ W2,
                                             const int* __restrict__ ei,
                                             unsigned short* __restrict__ W1t,
                                             unsigned short* __restrict__ W2t,
                                             int* __restrict__ cnt,
                                             int* __restrict__ rank) {
  const int bid = blockIdx.x, tid = threadIdx.x;
  if (bid < HIST_BLOCKS) {
    #pragma unroll
    for (int k = 0; k < 4; ++k) {
      int e = bid * 1024 + k * 256 + tid;
      if (e < N_EDGES) rank[e] = atomicAdd(&cnt[ei[e]], 1);
    }
  } else if (bid < HIST_BLOCKS + W1T_BLOCKS) {
    int gid = (bid - HIST_BLOCKS) * 256 + tid;       // W1t[n][k]
    int n = gid >> 9, k = gid & 511;
    W1t[gid] = f2bf(W1[(long)k * N_HID + n]);
  } else {
    int gid = (bid - HIST_BLOCKS - W1T_BLOCKS) * 256 + tid;  // W2t[n][k], n pad 48
    int n = gid >> 8, k = gid & 255;
    W2t[gid] = (n < N_CLASS) ? f2bf(W2[(long)k * N_CLASS + n]) : (unsigned short)0;
  }
}

// ---------------- scan (3 passes) ----------------
__global__ __launch_bounds__(1024) void k_scan_a(const int* __restrict__ cnt,
                                                 int* __restrict__ rp,
                                                 int* __restrict__ bsum) {
  __shared__ int sm[1024];
  const int tid = threadIdx.x;
  const int i = blockIdx.x * 1024 + tid;
  int v = (i < N_NODES) ? cnt[i] : 0;
  sm[tid] = v;
  __syncthreads();
  #pragma unroll
  for (int d = 1; d < 1024; d <<= 1) {
    int t = (tid >= d) ? sm[tid - d] : 0;
    __syncthreads();
    sm[tid] += t;
    __syncthreads();
  }
  if (i < N_NODES) rp[i] = sm[tid] - v;
  if (tid == 1023) bsum[blockIdx.x] = sm[1023];
}

__global__ __launch_bounds__(128) void k_scan_b(const int* __restrict__ bsum,
                                                int* __restrict__ boffs,
                                                int* __restrict__ rp) {
  __shared__ int sm[128];
  const int tid = threadIdx.x;
  const int nb = (N_NODES + 1023) >> 10;
  int v = (tid < nb) ? bsum[tid] : 0;
  sm[tid] = v;
  __syncthreads();
  #pragma unroll
  for (int d = 1; d < 128; d <<= 1) {
    int t = (tid >= d) ? sm[tid - d] : 0;
    __syncthreads();
    sm[tid] += t;
    __syncthreads();
  }
  boffs[tid] = sm[tid] - v;
  if (tid == 127) rp[N_NODES] = sm[127];
}

__global__ void k_scan_c(int* __restrict__ rp, const int* __restrict__ boffs) {
  int i = blockIdx.x * 256 + threadIdx.x;
  if (i >= N_NODES) return;
  rp[i] += boffs[i >> 10];
}

// ---------------- fused: GEMM1 m97-style (even blocks) + scatter (odd blocks) -----
// gemm: tile 128(M)x256(N)=full N, BK=32, 8 waves (2m x 4n), wave tile 64x64.
// A (f32) and B (bf16) staged via global_load_lds w=16, LINEAR LDS layout with
// both-sides XOR swizzle (pre-swizzled global source + swizzled frag read):
//   A[128][8 slots]: pslot = slot ^ (row&7)      -> conflict-free frag reads
//   B[256][4 slots]: pslot = slot ^ ((row>>2)&3) -> 2-way (free)
#define NG1 782
__global__ __launch_bounds__(512) void k_fused1(const float* __restrict__ X,
                                                const unsigned short* __restrict__ W1t,
                                                const float* __restrict__ b1,
                                                unsigned short* __restrict__ H1,
                                                const int* __restrict__ ei,
                                                const float* __restrict__ ew,
                                                const int* __restrict__ rank,
                                                const int* __restrict__ rp,
                                                int2* __restrict__ cw) {
  const int t = threadIdx.x;

  if (blockIdx.x & 1) {                    // ---- scatter role ----
    int sb = blockIdx.x >> 1;
    #pragma unroll
    for (int k = 0; k < 4; ++k) {
      int e = sb * 2048 + k * 512 + t;
      if (e < N_EDGES) {
        int r = ei[e];
        int pos = rp[r] + rank[e];
        cw[pos] = make_int2(ei[N_EDGES + e], __float_as_int(ew[e]));
      }
    }
    return;
  }

  // ---- gemm role ----
  __shared__ __align__(16) float As[128 * 32];          // 16 KB, linear swizzled
  __shared__ __align__(16) unsigned short Bsm[256 * 32]; // 16 KB, linear swizzled
  const int gb = blockIdx.x >> 1;
  const long m0 = (long)gb * 128;
  const int lane = t & 63;
  const int wid = t >> 6;
  const int wm = wid >> 2, wn = wid & 3;   // 2 x 4 wave grid, wave tile 64x64
  const int lr = lane & 15;
  const int lkg = lane >> 4;               // k-group 0..3

  // staging maps (thread -> linear LDS slot; source pre-swizzled)
  const int a_row = t >> 3, a_ps = t & 7;            // A: 64 rows per j
  const int b_row = t >> 2, b_ps = t & 3;            // B: 128 rows per j
  long a_gr0 = m0 + a_row;      if (a_gr0 >= N_NODES) a_gr0 = N_NODES - 1;
  long a_gr1 = m0 + 64 + a_row; if (a_gr1 >= N_NODES) a_gr1 = N_NODES - 1;
  const float* a_src0 = X + a_gr0 * N_FEAT + ((a_ps ^ (a_row & 7)) << 2);
  const float* a_src1 = X + a_gr1 * N_FEAT + ((a_ps ^ (a_row & 7)) << 2);
  const unsigned short* b_src0 = W1t + (long)b_row * N_FEAT + ((b_ps ^ ((b_row >> 2) & 3)) << 3);
  const unsigned short* b_src1 = W1t + (long)(128 + b_row) * N_FEAT + ((b_ps ^ ((b_row >> 2) & 3)) << 3);
  char* a_dst = (char*)As + wid * 1024;
  char* b_dst = (char*)Bsm + wid * 1024;

  f32x4 acc[4][4] = {};

  for (int k0 = 0; k0 < N_FEAT; k0 += 32) {
    gll16(a_src0 + k0, a_dst);
    gll16(a_src1 + k0, a_dst + 8192);
    gll16(b_src0 + k0, b_dst);
    gll16(b_src1 + k0, b_dst + 8192);
    __syncthreads();                       // drains vmcnt: tiles ready

    bf16x8 bv[4];
    #pragma unroll
    for (int nt = 0; nt < 4; ++nt) {
      int row = wn * 64 + nt * 16 + lr;
      int ps = lkg ^ ((lr >> 2) & 3);
      bv[nt] = *(const bf16x8*)((const char*)Bsm + row * 64 + ps * 16);
    }
    #pragma unroll
    for (int mt = 0; mt < 4; ++mt) {
      int row = wm * 64 + mt * 16 + lr;
      int s0 = (2 * lkg) ^ (lr & 7);
      int s1 = (2 * lkg + 1) ^ (lr & 7);
      f32x4 xa = *(const f32x4*)((const char*)As + row * 128 + s0 * 16);
      f32x4 xb = *(const f32x4*)((const char*)As + row * 128 + s1 * 16);
      bf16x8 av;
      av[0] = (__bf16)xa[0]; av[1] = (__bf16)xa[1];
      av[2] = (__bf16)xa[2]; av[3] = (__bf16)xa[3];
      av[4] = (__bf16)xb[0]; av[5] = (__bf16)xb[1];
      av[6] = (__bf16)xb[2]; av[7] = (__bf16)xb[3];
      #pragma unroll
      for (int nt = 0; nt < 4; ++nt)
        acc[mt][nt] = __builtin_amdgcn_mfma_f32_16x16x32_bf16(av, bv[nt], acc[mt][nt], 0, 0, 0);
    }
    __syncthreads();                       // frag reads done before restage
  }

  #pragma unroll
  for (int nt = 0; nt < 4; ++nt) {
    int col = wn * 64 + nt * 16 + lr;
    float bias = b1[col];
    #pragma unroll
    for (int mt = 0; mt < 4; ++mt) {
      #pragma unroll
      for (int i = 0; i < 4; ++i) {
        long row = m0 + wm * 64 + mt * 16 + lkg * 4 + i;
        if (row < N_NODES) H1[row * N_HID + col] = f2bf(acc[mt][nt][i] + bias);
      }
    }
  }
}

// ---------------- SPMM1 + relu: H1r = bf16(relu(A @ H1)), 8-deep gather pipeline ----
__global__ __launch_bounds__(256) void k_spmm1(const int* __restrict__ row_ptr,
                                               const int2* __restrict__ cw,
                                               const unsigned short* __restrict__ H1,
                                               unsigned short* __restrict__ H1r) {
  int r = blockIdx.x * 4 + (threadIdx.x >> 6);
  int lane = threadIdx.x & 63;
  if (r >= N_NODES) return;
  int s = row_ptr[r], e = row_ptr[r + 1];
  float a0 = 0.f, a1 = 0.f, a2 = 0.f, a3 = 0.f;
  const unsigned short* Hb = H1 + lane * 4;
  int i = s;
  for (; i + 8 <= e; i += 8) {
    int2 c0 = cw[i + 0]; int2 c1 = cw[i + 1]; int2 c2 = cw[i + 2]; int2 c3 = cw[i + 3];
    int2 c4 = cw[i + 4]; int2 c5 = cw[i + 5]; int2 c6 = cw[i + 6]; int2 c7 = cw[i + 7];
    u16x4 h0 = *(const u16x4*)(Hb + (long)c0.x * N_HID);
    u16x4 h1 = *(const u16x4*)(Hb + (long)c1.x * N_HID);
    u16x4 h2 = *(const u16x4*)(Hb + (long)c2.x * N_HID);
    u16x4 h3 = *(const u16x4*)(Hb + (long)c3.x * N_HID);
    u16x4 h4 = *(const u16x4*)(Hb + (long)c4.x * N_HID);
    u16x4 h5 = *(const u16x4*)(Hb + (long)c5.x * N_HID);
    u16x4 h6 = *(const u16x4*)(Hb + (long)c6.x * N_HID);
    u16x4 h7 = *(const u16x4*)(Hb + (long)c7.x * N_HID);
    float w0 = __int_as_float(c0.y), w1 = __int_as_float(c1.y);
    float w2 = __int_as_float(c2.y), w3 = __int_as_float(c3.y);
    float w4 = __int_as_float(c4.y), w5 = __int_as_float(c5.y);
    float w6 = __int_as_float(c6.y), w7 = __int_as_float(c7.y);
    a0 += w0 * bf2f(h0[0]); a1 += w0 * bf2f(h0[1]); a2 += w0 * bf2f(h0[2]); a3 += w0 * bf2f(h0[3]);
    a0 += w1 * bf2f(h1[0]); a1 += w1 * bf2f(h1[1]); a2 += w1 * bf2f(h1[2]); a3 += w1 * bf2f(h1[3]);
    a0 += w2 * bf2f(h2[0]); a1 += w2 * bf2f(h2[1]); a2 += w2 * bf2f(h2[2]); a3 += w2 * bf2f(h2[3]);
    a0 += w3 * bf2f(h3[0]); a1 += w3 * bf2f(h3[1]); a2 += w3 * bf2f(h3[2]); a3 += w3 * bf2f(h3[3]);
    a0 += w4 * bf2f(h4[0]); a1 += w4 * bf2f(h4[1]); a2 += w4 * bf2f(h4[2]); a3 += w4 * bf2f(h4[3]);
    a0 += w5 * bf2f(h5[0]); a1 += w5 * bf2f(h5[1]); a2 += w5 * bf2f(h5[2]); a3 += w5 * bf2f(h5[3]);
    a0 += w6 * bf2f(h6[0]); a1 += w6 * bf2f(h6[1]); a2 += w6 * bf2f(h6[2]); a3 += w6 * bf2f(h6[3]);
    a0 += w7 * bf2f(h7[0]); a1 += w7 * bf2f(h7[1]); a2 += w7 * bf2f(h7[2]); a3 += w7 * bf2f(h7[3]);
  }
  for (; i < e; ++i) {
    int2 cwv = cw[i];
    float w = __int_as_float(cwv.y);
    u16x4 hv = *(const u16x4*)(Hb + (long)cwv.x * N_HID);
    a0 += w * bf2f(hv[0]);
    a1 += w * bf2f(hv[1]);
    a2 += w * bf2f(hv[2]);
    a3 += w * bf2f(hv[3]);
  }
  u16x4 o;
  o[0] = f2bf(fmaxf(a0, 0.f));
  o[1] = f2bf(fmaxf(a1, 0.f));
  o[2] = f2bf(fmaxf(a2, 0.f));
  o[3] = f2bf(fmaxf(a3, 0.f));
  *(u16x4*)(H1r + (long)r * N_HID + lane * 4) = o;
}

// ---------------- GEMM2 direct-from-global: H2[.][48] = H1r @ W2 + b2 -------------
__global__ __launch_bounds__(256) void k_gemm2(const unsigned short* __restrict__ H1r,
                                               const unsigned short* __restrict__ W2t,
                                               const float* __restrict__ b2,
                                               float* __restrict__ H2) {
  const int t = threadIdx.x;
  const int lane = t & 63;
  const int wid = t >> 6;
  const long m0 = (long)blockIdx.x * 128;
  const int lr = lane & 15;
  const int lk = (lane >> 4) * 8;

  const unsigned short* Ab[2];
  #pragma unroll
  for (int mt = 0; mt < 2; ++mt) {
    long r = m0 + wid * 32 + mt * 16 + lr;
    if (r >= N_NODES) r = N_NODES - 1;
    Ab[mt] = H1r + r * N_HID + lk;
  }
  const unsigned short* Bb[3];
  #pragma unroll
  for (int nt = 0; nt < 3; ++nt)
    Bb[nt] = W2t + (long)(nt * 16 + lr) * N_HID + lk;

  f32x4 acc[2][3] = {};
  #pragma unroll
  for (int k0 = 0; k0 < N_HID; k0 += 32) {
    bf16x8 av[2], bvv[3];
    #pragma unroll
    for (int mt = 0; mt < 2; ++mt) av[mt] = *(const bf16x8*)(Ab[mt] + k0);
    #pragma unroll
    for (int nt = 0; nt < 3; ++nt) bvv[nt] = *(const bf16x8*)(Bb[nt] + k0);
    #pragma unroll
    for (int mt = 0; mt < 2; ++mt)
      #pragma unroll
      for (int nt = 0; nt < 3; ++nt)
        acc[mt][nt] = __builtin_amdgcn_mfma_f32_16x16x32_bf16(av[mt], bvv[nt], acc[mt][nt], 0, 0, 0);
  }

  #pragma unroll
  for (int nt = 0; nt < 3; ++nt) {
    int col = nt * 16 + lr;
    if (col < N_CLASS) {
      float bias = b2[col];
      #pragma unroll
      for (int mt = 0; mt < 2; ++mt) {
        #pragma unroll
        for (int i = 0; i < 4; ++i) {
          long row = m0 + wid * 32 + mt * 16 + (lane >> 4) * 4 + i;
          if (row < N_NODES) H2[row * H2S + col] = acc[mt][nt][i] + bias;
        }
      }
    }
  }
}

// ---------------- SPMM2 + log_softmax fused, 8-deep gather pipeline ----------------
__global__ __launch_bounds__(256) void k_spmm2_lsm(const int* __restrict__ row_ptr,
                                                   const int2* __restrict__ cw,
                                                   const float* __restrict__ H2,
                                                   float* __restrict__ out) {
  int r = blockIdx.x * 4 + (threadIdx.x >> 6);
  int lane = threadIdx.x & 63;
  if (r >= N_NODES) return;
  int s = row_ptr[r], e = row_ptr[r + 1];
  float acc = 0.f;
  const bool act = lane < N_CLASS;
  int i = s;
  for (; i + 8 <= e; i += 8) {
    int2 c0 = cw[i + 0]; int2 c1 = cw[i + 1]; int2 c2 = cw[i + 2]; int2 c3 = cw[i + 3];
    int2 c4 = cw[i + 4]; int2 c5 = cw[i + 5]; int2 c6 = cw[i + 6]; int2 c7 = cw[i + 7];
    float h0 = 0.f, h1 = 0.f, h2 = 0.f, h3 = 0.f, h4 = 0.f, h5 = 0.f, h6 = 0.f, h7 = 0.f;
    if (act) {
      h0 = H2[(long)c0.x * H2S + lane];
      h1 = H2[(long)c1.x * H2S + lane];
      h2 = H2[(long)c2.x * H2S + lane];
      h3 = H2[(long)c3.x * H2S + lane];
      h4 = H2[(long)c4.x * H2S + lane];
      h5 = H2[(long)c5.x * H2S + lane];
      h6 = H2[(long)c6.x * H2S + lane];
      h7 = H2[(long)c7.x * H2S + lane];
    }
    acc += __int_as_float(c0.y) * h0;
    acc += __int_as_float(c1.y) * h1;
    acc += __int_as_float(c2.y) * h2;
    acc += __int_as_float(c3.y) * h3;
    acc += __int_as_float(c4.y) * h4;
    acc += __int_as_float(c5.y) * h5;
    acc += __int_as_float(c6.y) * h6;
    acc += __int_as_float(c7.y) * h7;
  }
  for (; i < e; ++i) {
    int2 cwv = cw[i];
    if (act) acc += __int_as_float(cwv.y) * H2[(long)cwv.x * H2S + lane];
  }
  float v = act ? acc : -INFINITY;
  float m = v;
  #pragma unroll
  for (int d = 32; d > 0; d >>= 1) m = fmaxf(m, __shfl_xor(m, d));
  float ex = act ? __expf(v - m) : 0.f;
  float ssum = ex;
  #pragma unroll
  for (int d = 32; d > 0; d >>= 1) ssum += __shfl_xor(ssum, d);
  float ls = __logf(ssum);
  if (act) out[(long)r * N_CLASS + lane] = v - m - ls;
}

extern "C" void kernel_launch(void* const* d_in, const int* in_sizes, int n_in,
                              void* d_out, int out_size, void* d_ws, size_t ws_size,
                              hipStream_t stream) {
  (void)in_sizes; (void)n_in; (void)out_size; (void)ws_size;
  const float* X  = (const float*)d_in[0];
  const int*   EI = (const int*)d_in[1];
  const float* EW = (const float*)d_in[2];
  const float* W1 = (const float*)d_in[3];
  const float* b1 = (const float*)d_in[4];
  const float* W2 = (const float*)d_in[5];
  const float* b2 = (const float*)d_in[6];
  float* out = (float*)d_out;

  char* p = (char*)d_ws;
  auto take = [&](size_t bytes) {
    char* r = p;
    p += (bytes + 511) & ~(size_t)511;
    return r;
  };
  unsigned short* W1t   = (unsigned short*)take((size_t)N_HID * N_FEAT * 2);
  unsigned short* W2t   = (unsigned short*)take((size_t)48 * N_HID * 2);
  int*            cnt   = (int*)take((size_t)N_NODES * 4);
  int*            rp    = (int*)take((size_t)(N_NODES + 1) * 4);
  int*            bsum  = (int*)take((size_t)128 * 4);
  int*            boffs = (int*)take((size_t)128 * 4);
  int*            rank  = (int*)take((size_t)N_EDGES * 4);
  int2*           cw    = (int2*)take((size_t)N_EDGES * 8);
  unsigned short* H1    = (unsigned short*)take((size_t)N_NODES * N_HID * 2);
  unsigned short* H1r   = (unsigned short*)take((size_t)N_NODES * N_HID * 2);
  float*          H2    = (float*)take((size_t)N_NODES * H2S * 4);

  const int NB_SCAN = (N_NODES + 1023) / 1024;

  hipMemsetAsync(cnt, 0, (size_t)N_NODES * 4, stream);
  k_pre<<<HIST_BLOCKS + W1T_BLOCKS + W2T_BLOCKS, 256, 0, stream>>>(W1, W2, EI, W1t, W2t, cnt, rank);
  k_scan_a<<<NB_SCAN, 1024, 0, stream>>>(cnt, rp, bsum);
  k_scan_b<<<1, 128, 0, stream>>>(bsum, boffs, rp);
  k_scan_c<<<(N_NODES + 255) / 256, 256, 0, stream>>>(rp, boffs);
  k_fused1<<<2 * NG1, 512, 0, stream>>>(X, W1t, b1, H1, EI, EW, rank, rp, cw);
  k_spmm1<<<(N_NODES + 3) / 4, 256, 0, stream>>>(rp, cw, H1, H1r);
  k_gemm2<<<(N_NODES + 127) / 128, 256, 0, stream>>>(H1r, W2t, b2, H2);
  k_spmm2_lsm<<<(N_NODES + 3) / 4, 256, 0, stream>>>(rp, cw, H2, out);
}

// Round 8
// 427.048 us; speedup vs baseline: 1.5688x; 1.0805x over previous
//
#include <hip/hip_runtime.h>
#include <stdint.h>

#define N_NODES 100000
#define N_EDGES 1600000
#define N_FEAT 512
#define N_HID 256
#define N_CLASS 40
#define H2S 48                      // padded H2 row stride (floats)

typedef float f32x4 __attribute__((ext_vector_type(4)));
typedef __bf16 bf16x8 __attribute__((ext_vector_type(8)));
typedef unsigned short u16x4 __attribute__((ext_vector_type(4)));
typedef unsigned short u16x8 __attribute__((ext_vector_type(8)));

__device__ __forceinline__ unsigned short f2bf(float f) {
  unsigned int u = __float_as_uint(f);
  unsigned int r = (u + 0x7FFFu + ((u >> 16) & 1u)) >> 16;
  return (unsigned short)r;
}
__device__ __forceinline__ float bf2f(unsigned short s) {
  return __uint_as_float(((unsigned int)s) << 16);
}
// packed edge: bits [31:17] = bf16(w) sans sign, [16:0] = col
__device__ __forceinline__ float pk_w(unsigned int p) {
  return __uint_as_float((p >> 17) << 16);
}
__device__ __forceinline__ int pk_c(unsigned int p) { return (int)(p & 0x1FFFFu); }

// ---------------- preamble: W1 transpose+cvt | W2 transpose+cvt | hist(+rank) ------
#define HIST_BLOCKS 1563
#define W1T_BLOCKS  512
#define W2T_BLOCKS  48
__global__ __launch_bounds__(256) void k_pre(const float* __restrict__ W1,
                                             const float* __restrict__ W2,
                                             const int* __restrict__ ei,
                                             unsigned short* __restrict__ W1t,
                                             unsigned short* __restrict__ W2t,
                                             int* __restrict__ cnt,
                                             int* __restrict__ rank) {
  const int bid = blockIdx.x, tid = threadIdx.x;
  if (bid < HIST_BLOCKS) {
    #pragma unroll
    for (int k = 0; k < 4; ++k) {
      int e = bid * 1024 + k * 256 + tid;
      if (e < N_EDGES) rank[e] = atomicAdd(&cnt[ei[e]], 1);
    }
  } else if (bid < HIST_BLOCKS + W1T_BLOCKS) {
    int gid = (bid - HIST_BLOCKS) * 256 + tid;       // W1t[n][k]
    int n = gid >> 9, k = gid & 511;
    W1t[gid] = f2bf(W1[(long)k * N_HID + n]);
  } else {
    int gid = (bid - HIST_BLOCKS - W1T_BLOCKS) * 256 + tid;  // W2t[n][k], n pad 48
    int n = gid >> 8, k = gid & 255;
    W2t[gid] = (n < N_CLASS) ? f2bf(W2[(long)k * N_CLASS + n]) : (unsigned short)0;
  }
}

// ---------------- scan (3 passes) ----------------
__global__ __launch_bounds__(1024) void k_scan_a(const int* __restrict__ cnt,
                                                 int* __restrict__ rp,
                                                 int* __restrict__ bsum) {
  __shared__ int sm[1024];
  const int tid = threadIdx.x;
  const int i = blockIdx.x * 1024 + tid;
  int v = (i < N_NODES) ? cnt[i] : 0;
  sm[tid] = v;
  __syncthreads();
  #pragma unroll
  for (int d = 1; d < 1024; d <<= 1) {
    int t = (tid >= d) ? sm[tid - d] : 0;
    __syncthreads();
    sm[tid] += t;
    __syncthreads();
  }
  if (i < N_NODES) rp[i] = sm[tid] - v;
  if (tid == 1023) bsum[blockIdx.x] = sm[1023];
}

__global__ __launch_bounds__(128) void k_scan_b(const int* __restrict__ bsum,
                                                int* __restrict__ boffs,
                                                int* __restrict__ rp) {
  __shared__ int sm[128];
  const int tid = threadIdx.x;
  const int nb = (N_NODES + 1023) >> 10;
  int v = (tid < nb) ? bsum[tid] : 0;
  sm[tid] = v;
  __syncthreads();
  #pragma unroll
  for (int d = 1; d < 128; d <<= 1) {
    int t = (tid >= d) ? sm[tid - d] : 0;
    __syncthreads();
    sm[tid] += t;
    __syncthreads();
  }
  boffs[tid] = sm[tid] - v;
  if (tid == 127) rp[N_NODES] = sm[127];
}

__global__ void k_scan_c(int* __restrict__ rp, const int* __restrict__ boffs) {
  int i = blockIdx.x * 256 + threadIdx.x;
  if (i >= N_NODES) return;
  rp[i] += boffs[i >> 10];
}

// ---------------- scatter: packed 4B records, no atomics ----------------
__global__ __launch_bounds__(512) void k_scatter(const int* __restrict__ ei,
                                                 const float* __restrict__ ew,
                                                 const int* __restrict__ rank,
                                                 const int* __restrict__ rp,
                                                 unsigned int* __restrict__ cwp) {
  const int t = threadIdx.x;
  #pragma unroll
  for (int k = 0; k < 4; ++k) {
    int e = blockIdx.x * 2048 + k * 512 + t;
    if (e < N_EDGES) {
      int r = ei[e];
      int pos = rp[r] + rank[e];
      unsigned int w15 = (unsigned int)f2bf(ew[e]);      // sign always 0
      cwp[pos] = (w15 << 17) | (unsigned int)ei[N_EDGES + e];
    }
  }
}

// ---------------- GEMM1 v2: B-resident LDS, barrier-free M-streaming ----------------
// 250 blocks = 125 row-ranges (800 rows) x 2 col-panels (128). 1024 thr = 16 waves.
// Bs[col 0..127][k 0..511] bf16, slot-XOR swizzled, staged ONCE (128 KB).
// Each wave independently does 16-row chunks: K-loop has NO barriers.
__global__ __launch_bounds__(1024) void k_gemm1(const float* __restrict__ X,
                                                const unsigned short* __restrict__ W1t,
                                                const float* __restrict__ b1,
                                                unsigned short* __restrict__ H1) {
  __shared__ __align__(16) unsigned short Bs[128 * 512];   // 128 KB
  const int t = threadIdx.x;
  const int pair = blockIdx.x >> 1, panel = blockIdx.x & 1;
  const long rb = (long)pair * 800;
  const int n0 = panel * 128;

  // ---- stage B once: thread t -> col t>>3, slot segment t&7 (8 slots of 8 shorts)
  {
    const int col = t >> 3, seg = t & 7;
    const unsigned short* src = W1t + (long)(n0 + col) * N_FEAT;
    #pragma unroll
    for (int j = 0; j < 8; ++j) {
      int slot = seg * 8 + j;
      int ps = slot ^ (col & 7);
      *(u16x8*)&Bs[col * 512 + ps * 8] = *(const u16x8*)(src + slot * 8);
    }
  }
  __syncthreads();

  const int lane = t & 63;
  const int wid = t >> 6;                  // 0..15
  const int lr = lane & 15;
  const int lkg = lane >> 4;               // 0..3

  for (int c = wid; c < 50; c += 16) {     // 16-row chunks, waves independent
    const long row0 = rb + c * 16;
    const float* ap = X + (row0 + lr) * N_FEAT + lkg * 8;
    f32x4 acc[8] = {};

    #pragma unroll 2
    for (int k0 = 0; k0 < N_FEAT; k0 += 32) {
      f32x4 xa = *(const f32x4*)(ap + k0);
      f32x4 xb = *(const f32x4*)(ap + k0 + 4);
      bf16x8 av;
      av[0] = (__bf16)xa[0]; av[1] = (__bf16)xa[1];
      av[2] = (__bf16)xa[2]; av[3] = (__bf16)xa[3];
      av[4] = (__bf16)xb[0]; av[5] = (__bf16)xb[1];
      av[6] = (__bf16)xb[2]; av[7] = (__bf16)xb[3];
      const int slot = (k0 >> 3) + lkg;
      const int ps = slot ^ (lr & 7);
      #pragma unroll
      for (int nt = 0; nt < 8; ++nt) {
        bf16x8 bv = *(const bf16x8*)&Bs[(nt * 16 + lr) * 512 + ps * 8];
        acc[nt] = __builtin_amdgcn_mfma_f32_16x16x32_bf16(av, bv, acc[nt], 0, 0, 0);
      }
    }

    #pragma unroll
    for (int nt = 0; nt < 8; ++nt) {
      int colg = n0 + nt * 16 + lr;
      float bias = b1[colg];
      #pragma unroll
      for (int i = 0; i < 4; ++i) {
        long row = row0 + lkg * 4 + i;
        H1[row * N_HID + colg] = f2bf(acc[nt][i] + bias);
      }
    }
  }
}

// ---------------- SPMM1 + relu: H1r = bf16(relu(A @ H1)), 8-deep, packed edges ----
__global__ __launch_bounds__(256) void k_spmm1(const int* __restrict__ row_ptr,
                                               const unsigned int* __restrict__ cwp,
                                               const unsigned short* __restrict__ H1,
                                               unsigned short* __restrict__ H1r) {
  int r = blockIdx.x * 4 + (threadIdx.x >> 6);
  int lane = threadIdx.x & 63;
  if (r >= N_NODES) return;
  int s = row_ptr[r], e = row_ptr[r + 1];
  float a0 = 0.f, a1 = 0.f, a2 = 0.f, a3 = 0.f;
  const unsigned short* Hb = H1 + lane * 4;
  int i = s;
  for (; i + 8 <= e; i += 8) {
    uint4 ca = *(const uint4*)(cwp + i);
    uint4 cb = *(const uint4*)(cwp + i + 4);
    u16x4 h0 = *(const u16x4*)(Hb + (long)pk_c(ca.x) * N_HID);
    u16x4 h1 = *(const u16x4*)(Hb + (long)pk_c(ca.y) * N_HID);
    u16x4 h2 = *(const u16x4*)(Hb + (long)pk_c(ca.z) * N_HID);
    u16x4 h3 = *(const u16x4*)(Hb + (long)pk_c(ca.w) * N_HID);
    u16x4 h4 = *(const u16x4*)(Hb + (long)pk_c(cb.x) * N_HID);
    u16x4 h5 = *(const u16x4*)(Hb + (long)pk_c(cb.y) * N_HID);
    u16x4 h6 = *(const u16x4*)(Hb + (long)pk_c(cb.z) * N_HID);
    u16x4 h7 = *(const u16x4*)(Hb + (long)pk_c(cb.w) * N_HID);
    float w0 = pk_w(ca.x), w1 = pk_w(ca.y), w2 = pk_w(ca.z), w3 = pk_w(ca.w);
    float w4 = pk_w(cb.x), w5 = pk_w(cb.y), w6 = pk_w(cb.z), w7 = pk_w(cb.w);
    a0 += w0 * bf2f(h0[0]); a1 += w0 * bf2f(h0[1]); a2 += w0 * bf2f(h0[2]); a3 += w0 * bf2f(h0[3]);
    a0 += w1 * bf2f(h1[0]); a1 += w1 * bf2f(h1[1]); a2 += w1 * bf2f(h1[2]); a3 += w1 * bf2f(h1[3]);
    a0 += w2 * bf2f(h2[0]); a1 += w2 * bf2f(h2[1]); a2 += w2 * bf2f(h2[2]); a3 += w2 * bf2f(h2[3]);
    a0 += w3 * bf2f(h3[0]); a1 += w3 * bf2f(h3[1]); a2 += w3 * bf2f(h3[2]); a3 += w3 * bf2f(h3[3]);
    a0 += w4 * bf2f(h4[0]); a1 += w4 * bf2f(h4[1]); a2 += w4 * bf2f(h4[2]); a3 += w4 * bf2f(h4[3]);
    a0 += w5 * bf2f(h5[0]); a1 += w5 * bf2f(h5[1]); a2 += w5 * bf2f(h5[2]); a3 += w5 * bf2f(h5[3]);
    a0 += w6 * bf2f(h6[0]); a1 += w6 * bf2f(h6[1]); a2 += w6 * bf2f(h6[2]); a3 += w6 * bf2f(h6[3]);
    a0 += w7 * bf2f(h7[0]); a1 += w7 * bf2f(h7[1]); a2 += w7 * bf2f(h7[2]); a3 += w7 * bf2f(h7[3]);
  }
  for (; i < e; ++i) {
    unsigned int p = cwp[i];
    float w = pk_w(p);
    u16x4 hv = *(const u16x4*)(Hb + (long)pk_c(p) * N_HID);
    a0 += w * bf2f(hv[0]);
    a1 += w * bf2f(hv[1]);
    a2 += w * bf2f(hv[2]);
    a3 += w * bf2f(hv[3]);
  }
  u16x4 o;
  o[0] = f2bf(fmaxf(a0, 0.f));
  o[1] = f2bf(fmaxf(a1, 0.f));
  o[2] = f2bf(fmaxf(a2, 0.f));
  o[3] = f2bf(fmaxf(a3, 0.f));
  *(u16x4*)(H1r + (long)r * N_HID + lane * 4) = o;
}

// ---------------- GEMM2 direct-from-global: H2[.][48] = H1r @ W2 + b2 -------------
__global__ __launch_bounds__(256) void k_gemm2(const unsigned short* __restrict__ H1r,
                                               const unsigned short* __restrict__ W2t,
                                               const float* __restrict__ b2,
                                               float* __restrict__ H2) {
  const int t = threadIdx.x;
  const int lane = t & 63;
  const int wid = t >> 6;
  const long m0 = (long)blockIdx.x * 128;
  const int lr = lane & 15;
  const int lk = (lane >> 4) * 8;

  const unsigned short* Ab[2];
  #pragma unroll
  for (int mt = 0; mt < 2; ++mt) {
    long r = m0 + wid * 32 + mt * 16 + lr;
    if (r >= N_NODES) r = N_NODES - 1;
    Ab[mt] = H1r + r * N_HID + lk;
  }
  const unsigned short* Bb[3];
  #pragma unroll
  for (int nt = 0; nt < 3; ++nt)
    Bb[nt] = W2t + (long)(nt * 16 + lr) * N_HID + lk;

  f32x4 acc[2][3] = {};
  #pragma unroll
  for (int k0 = 0; k0 < N_HID; k0 += 32) {
    bf16x8 av[2], bvv[3];
    #pragma unroll
    for (int mt = 0; mt < 2; ++mt) av[mt] = *(const bf16x8*)(Ab[mt] + k0);
    #pragma unroll
    for (int nt = 0; nt < 3; ++nt) bvv[nt] = *(const bf16x8*)(Bb[nt] + k0);
    #pragma unroll
    for (int mt = 0; mt < 2; ++mt)
      #pragma unroll
      for (int nt = 0; nt < 3; ++nt)
        acc[mt][nt] = __builtin_amdgcn_mfma_f32_16x16x32_bf16(av[mt], bvv[nt], acc[mt][nt], 0, 0, 0);
  }

  #pragma unroll
  for (int nt = 0; nt < 3; ++nt) {
    int col = nt * 16 + lr;
    if (col < N_CLASS) {
      float bias = b2[col];
      #pragma unroll
      for (int mt = 0; mt < 2; ++mt) {
        #pragma unroll
        for (int i = 0; i < 4; ++i) {
          long row = m0 + wid * 32 + mt * 16 + (lane >> 4) * 4 + i;
          if (row < N_NODES) H2[row * H2S + col] = acc[mt][nt][i] + bias;
        }
      }
    }
  }
}

// ---------------- SPMM2 + log_softmax fused, 8-deep, packed edges ----------------
__global__ __launch_bounds__(256) void k_spmm2_lsm(const int* __restrict__ row_ptr,
                                                   const unsigned int* __restrict__ cwp,
                                                   const float* __restrict__ H2,
                                                   float* __restrict__ out) {
  int r = blockIdx.x * 4 + (threadIdx.x >> 6);
  int lane = threadIdx.x & 63;
  if (r >= N_NODES) return;
  int s = row_ptr[r], e = row_ptr[r + 1];
  float acc = 0.f;
  const bool act = lane < N_CLASS;
  int i = s;
  for (; i + 8 <= e; i += 8) {
    uint4 ca = *(const uint4*)(cwp + i);
    uint4 cb = *(const uint4*)(cwp + i + 4);
    float h0 = 0.f, h1 = 0.f, h2 = 0.f, h3 = 0.f, h4 = 0.f, h5 = 0.f, h6 = 0.f, h7 = 0.f;
    if (act) {
      h0 = H2[(long)pk_c(ca.x) * H2S + lane];
      h1 = H2[(long)pk_c(ca.y) * H2S + lane];
      h2 = H2[(long)pk_c(ca.z) * H2S + lane];
      h3 = H2[(long)pk_c(ca.w) * H2S + lane];
      h4 = H2[(long)pk_c(cb.x) * H2S + lane];
      h5 = H2[(long)pk_c(cb.y) * H2S + lane];
      h6 = H2[(long)pk_c(cb.z) * H2S + lane];
      h7 = H2[(long)pk_c(cb.w) * H2S + lane];
    }
    acc += pk_w(ca.x) * h0;
    acc += pk_w(ca.y) * h1;
    acc += pk_w(ca.z) * h2;
    acc += pk_w(ca.w) * h3;
    acc += pk_w(cb.x) * h4;
    acc += pk_w(cb.y) * h5;
    acc += pk_w(cb.z) * h6;
    acc += pk_w(cb.w) * h7;
  }
  for (; i < e; ++i) {
    unsigned int p = cwp[i];
    if (act) acc += pk_w(p) * H2[(long)pk_c(p) * H2S + lane];
  }
  float v = act ? acc : -INFINITY;
  float m = v;
  #pragma unroll
  for (int d = 32; d > 0; d >>= 1) m = fmaxf(m, __shfl_xor(m, d));
  float ex = act ? __expf(v - m) : 0.f;
  float ssum = ex;
  #pragma unroll
  for (int d = 32; d > 0; d >>= 1) ssum += __shfl_xor(ssum, d);
  float ls = __logf(ssum);
  if (act) out[(long)r * N_CLASS + lane] = v - m - ls;
}

extern "C" void kernel_launch(void* const* d_in, const int* in_sizes, int n_in,
                              void* d_out, int out_size, void* d_ws, size_t ws_size,
                              hipStream_t stream) {
  (void)in_sizes; (void)n_in; (void)out_size; (void)ws_size;
  const float* X  = (const float*)d_in[0];
  const int*   EI = (const int*)d_in[1];
  const float* EW = (const float*)d_in[2];
  const float* W1 = (const float*)d_in[3];
  const float* b1 = (const float*)d_in[4];
  const float* W2 = (const float*)d_in[5];
  const float* b2 = (const float*)d_in[6];
  float* out = (float*)d_out;

  char* p = (char*)d_ws;
  auto take = [&](size_t bytes) {
    char* r = p;
    p += (bytes + 511) & ~(size_t)511;
    return r;
  };
  unsigned short* W1t   = (unsigned short*)take((size_t)N_HID * N_FEAT * 2);
  unsigned short* W2t   = (unsigned short*)take((size_t)48 * N_HID * 2);
  int*            cnt   = (int*)take((size_t)N_NODES * 4);
  int*            rp    = (int*)take((size_t)(N_NODES + 1) * 4);
  int*            bsum  = (int*)take((size_t)128 * 4);
  int*            boffs = (int*)take((size_t)128 * 4);
  int*            rank  = (int*)take((size_t)N_EDGES * 4);
  unsigned int*   cwp   = (unsigned int*)take((size_t)N_EDGES * 4);
  unsigned short* H1    = (unsigned short*)take((size_t)N_NODES * N_HID * 2);
  unsigned short* H1r   = (unsigned short*)take((size_t)N_NODES * N_HID * 2);
  float*          H2    = (float*)take((size_t)N_NODES * H2S * 4);

  const int NB_SCAN = (N_NODES + 1023) / 1024;

  hipMemsetAsync(cnt, 0, (size_t)N_NODES * 4, stream);
  k_pre<<<HIST_BLOCKS + W1T_BLOCKS + W2T_BLOCKS, 256, 0, stream>>>(W1, W2, EI, W1t, W2t, cnt, rank);
  k_scan_a<<<NB_SCAN, 1024, 0, stream>>>(cnt, rp, bsum);
  k_scan_b<<<1, 128, 0, stream>>>(bsum, boffs, rp);
  k_scan_c<<<(N_NODES + 255) / 256, 256, 0, stream>>>(rp, boffs);
  k_scatter<<<(N_EDGES + 2047) / 2048, 512, 0, stream>>>(EI, EW, rank, rp, cwp);
  k_gemm1<<<250, 1024, 0, stream>>>(X, W1t, b1, H1);
  k_spmm1<<<(N_NODES + 3) / 4, 256, 0, stream>>>(rp, cwp, H1, H1r);
  k_gemm2<<<(N_NODES + 127) / 128, 256, 0, stream>>>(H1r, W2t, b2, H2);
  k_spmm2_lsm<<<(N_NODES + 3) / 4, 256, 0, stream>>>(rp, cwp, H2, out);
}